// Round 7
// baseline (191.215 us; speedup 1.0000x reference)
//
#include <hip/hip_runtime.h>

// Problem constants
#define NB 64
#define NP 500
#define NC 128
#define NH 256
#define EPS_BN 1e-5f

// Edge-list geometry: 64 batches x 8 j-tiles, cap 1024 edges/segment
#define SEGS 8
#define CAPE 1024

// ws layout (float/int words)
#define EDGE_OFF 0
#define CNT_OFF (NB * SEGS * CAPE)   // 524288 (512 words)
#define CT_OFF (CNT_OFF + 512)       // c matrix, feature-major [256][64]

// Output layout: tc[64] | tsys[64] | l2_points[4096000] | correlation[8192]
#define OUT_PTS_OFF 128
#define OUT_CORR_OFF 4096128
#define TOTAL_F4 1024000  // 4,096,000 floats / 4

// k1 grid: scan 0..511 | misc 512..575 | copy 576..1599
#define SCAN_BLKS 512
#define MISC_END 576
#define K1_COPY 1024
#define K1_GRID (MISC_END + K1_COPY)

// k3 activation LDS stride (shorts): 264 = 256 + 8 pad -> ds_read_b128 from
// [b][k] hits all 8 bank-groups uniformly (132 words/row = 4 mod 32).
#define XS 264

typedef __attribute__((ext_vector_type(8))) short short8b;  // 8 bf16
typedef __attribute__((ext_vector_type(4))) float f32x4;

__device__ __forceinline__ short bfh(float f) {
  return (short)(__builtin_bit_cast(unsigned, f) >> 16);  // truncate to bf16
}
__device__ __forceinline__ float bff(short h) {
  return __builtin_bit_cast(float, ((unsigned)(unsigned short)h) << 16);
}

// ---------------------------------------------------------------------------
// K1: pair scan (512 = b x 8 j-tiles) + per-batch misc (64) + full pts copy.
// (Verbatim from the harness-verified baseline.)
// ---------------------------------------------------------------------------
__global__ __launch_bounds__(256) void k1_scan_misc_copy(
    const float* __restrict__ xyz,    // [B,3,N]
    const float* __restrict__ temp,   // [B,1,N]
    const float* __restrict__ l3,     // [B,C]
    const float* __restrict__ pts,    // [B,C,N] l2_points
    float* __restrict__ out,
    float* __restrict__ ws) {
  const int blk = blockIdx.x;
  const int tid = threadIdx.x;

  if (blk < SCAN_BLKS) {
    const int b = blk >> 3;
    const int jt = blk & 7;
    __shared__ float4 pt[NP];  // x,y,z,s
    __shared__ int lcnt;
    if (tid == 0) lcnt = 0;
    const float* xr = xyz + b * 1500;
    for (int idx = tid; idx < NP; idx += 256) {
      float x = xr[idx], y = xr[500 + idx], z = xr[1000 + idx];
      pt[idx] = make_float4(x, y, z, x * x + y * y + z * z);
    }
    __syncthreads();

    const int j0 = jt * 63;
    const int j1 = (j0 + 63 < NP) ? j0 + 63 : NP;
    const int i0 = tid;
    const int i1 = tid + 256;
    float4 p0 = pt[i0];
    float4 p1 = (i1 < NP) ? pt[i1] : make_float4(0.f, 0.f, 0.f, 0.f);
    int* eseg = (int*)ws + EDGE_OFF + (b * SEGS + jt) * CAPE;

    for (int j = j0; j < j1; ++j) {
      float4 q = pt[j];  // wave-uniform -> LDS broadcast
      if (i0 < j) {
        float sq = p0.w + q.w - 2.f * (p0.x * q.x + p0.y * q.y + p0.z * q.z);
        float d = sqrtf(fabsf(sq));
        if (d > 0.19f && d < 0.21f) {
          int e = atomicAdd(&lcnt, 1);
          if (e < CAPE) eseg[e] = (i0 << 16) | j;
        }
      }
      if (i1 < j) {  // implies i1 < 500
        float sq = p1.w + q.w - 2.f * (p1.x * q.x + p1.y * q.y + p1.z * q.z);
        float d = sqrtf(fabsf(sq));
        if (d > 0.19f && d < 0.21f) {
          int e = atomicAdd(&lcnt, 1);
          if (e < CAPE) eseg[e] = (i1 << 16) | j;
        }
      }
    }
    __syncthreads();
    if (tid == 0) {
      int c = lcnt < CAPE ? lcnt : CAPE;
      ((int*)ws)[CNT_OFF + b * SEGS + jt] = c;
    }
  } else if (blk < MISC_END) {
    // misc per batch: tsys, cT sa4 rows
    const int b = blk - SCAN_BLKS;
    float sum = 0.f;
    for (int i = tid; i < NP; i += 256) sum += temp[b * NP + i];
    for (int off = 32; off; off >>= 1) sum += __shfl_xor(sum, off);
    __shared__ float wsum[4];
    if ((tid & 63) == 0) wsum[tid >> 6] = sum;
    __syncthreads();
    if (tid == 0)
      out[64 + b] = (wsum[0] + wsum[1] + wsum[2] + wsum[3]) * (1.f / 500.f);
    if (tid < NC) ws[CT_OFF + (NC + tid) * 64 + b] = l3[b * NC + tid];
  } else {
    // copy all of l2_points -> out (also warms LLC for k2's re-read)
    const int cb = blk - MISC_END;
    const float4* src = (const float4*)pts;
    float4* dst = (float4*)(out + OUT_PTS_OFF);
    for (int idx = cb * 256 + tid; idx < TOTAL_F4; idx += K1_COPY * 256)
      dst[idx] = src[idx];
  }
}

// ---------------------------------------------------------------------------
// K2: correlation (512 = b x 8 chan-groups). Verbatim verified edge math.
// ---------------------------------------------------------------------------
__global__ __launch_bounds__(256) void k2_corr(
    const float* __restrict__ data,  // l2_points [B,C,N]
    float* __restrict__ out,
    float* __restrict__ ws) {
  const int blk = blockIdx.x;
  const int tid = threadIdx.x;
  const int b = blk >> 3;
  const int c0 = (blk & 7) * 16;
  __shared__ float dT[NP * 20];  // [j][c] for 16 channels, stride 20
  __shared__ float corrp[16];
  if (tid < 16) corrp[tid] = 0.f;

  const float4* in4 = (const float4*)(data + (size_t)b * 64000 + c0 * 500);
  for (int idx = tid; idx < 2000; idx += 256) {
    float4 v = in4[idx];
    int c = idx / 125;
    int j = (idx - c * 125) * 4;
    dT[(j + 0) * 20 + c] = v.x;
    dT[(j + 1) * 20 + c] = v.y;
    dT[(j + 2) * 20 + c] = v.z;
    dT[(j + 3) * 20 + c] = v.w;
  }
  __syncthreads();

  const int quad = tid & 3;
  const int slot = tid >> 2;
  float4 acc = make_float4(0.f, 0.f, 0.f, 0.f);
  const int* cnts = (const int*)ws + CNT_OFF + b * SEGS;
  int Etot = 0;
  for (int seg = 0; seg < SEGS; ++seg) {
    int E = cnts[seg];
    Etot += E;
    const int* eseg = (const int*)ws + EDGE_OFF + (b * SEGS + seg) * CAPE;
    for (int e = slot; e < E; e += 64) {
      int ij = eseg[e];
      int i = ij >> 16, j = ij & 0xffff;
      const float4 a = *(const float4*)(dT + i * 20 + quad * 4);
      const float4 c4 = *(const float4*)(dT + j * 20 + quad * 4);
      acc.x += a.x * c4.x;
      acc.y += a.y * c4.y;
      acc.z += a.z * c4.z;
      acc.w += a.w * c4.w;
    }
  }
  for (int off = 4; off < 64; off <<= 1) {
    acc.x += __shfl_xor(acc.x, off);
    acc.y += __shfl_xor(acc.y, off);
    acc.z += __shfl_xor(acc.z, off);
    acc.w += __shfl_xor(acc.w, off);
  }
  if ((tid & 63) < 4) {
    atomicAdd(&corrp[quad * 4 + 0], acc.x);
    atomicAdd(&corrp[quad * 4 + 1], acc.y);
    atomicAdd(&corrp[quad * 4 + 2], acc.z);
    atomicAdd(&corrp[quad * 4 + 3], acc.w);
  }
  __syncthreads();
  if (tid < 16) {
    float denom = fmaxf(2.f * (float)Etot, 1.f);  // ordered count = 2E
    float v = 2.f * corrp[tid] / denom;           // ordered sum = 2*upper
    out[OUT_CORR_OFF + b * NC + c0 + tid] = v;
    ws[CT_OFF + (c0 + tid) * 64 + b] = v;
  }
}

// ---------------------------------------------------------------------------
// K3: 4-layer MLP in ONE workgroup, 512 thr = 8 waves, bf16x3 MFMA.
//
// Round-6 diagnosis: VGPR_Count=56 + WRITE_SIZE~0 means the compiler neither
// kept the weight prefetch in registers nor spilled it — the scheduler SANK
// each single-use load to its use site, serializing the fetch chain
// (4.9 GB/s, 122 us). Fix: __builtin_amdgcn_sched_barrier(0) at the top of
// each layer's MFMA phase pins all 32 dwordx4 loads above their uses ->
// issued back-to-back, one latency. Prefetch is also issued one phase early
// (L0 before c-staging; L+1 right after layer L's MFMA phase), so the BN
// phase hides the latency entirely. __launch_bounds__(512,2) gives the
// 256-VGPR cap this needs (~220 live worst case).
//
// Activations in LDS as bf16 hi/lo pairs xh/xl[b][k], stride XS; B-fragment
// = single ds_read_b128, conflict-free. Fragment maps identical to the
// round-4/5/6 harness-verified kernel. Bias omitted (BN mean cancels it).
// BN over batch = shfl_xor{1,2,4,8} in 16-lane groups. Layer 3 -> w4 dot.
// ---------------------------------------------------------------------------
__global__ __launch_bounds__(512, 2) void k3_mlp(
    const float* __restrict__ ws, const float* __restrict__ w0,
    const float* __restrict__ g0, const float* __restrict__ be0,
    const float* __restrict__ w1, const float* __restrict__ g1,
    const float* __restrict__ be1, const float* __restrict__ w2,
    const float* __restrict__ g2, const float* __restrict__ be2,
    const float* __restrict__ w3, const float* __restrict__ g3,
    const float* __restrict__ be3, const float* __restrict__ w4,
    const float* __restrict__ b4, float* __restrict__ out) {
  const int tid = threadIdx.x;
  const int lane = tid & 63;
  const int wv = tid >> 6;     // 0..7
  const int l15 = lane & 15;
  const int lg = lane >> 4;    // 0..3

  __shared__ unsigned short xh[NB * XS];  // 33,792 B
  __shared__ unsigned short xl[NB * XS];  // 33,792 B
  __shared__ float tcl[NB];

  const float* Ws[4] = {w0, w1, w2, w3};
  const float* Gs[4] = {g0, g1, g2, g3};
  const float* Bs[4] = {be0, be1, be2, be3};

  float wreg[2][64];  // one live copy; re-filled per layer
  auto prefetch = [&](const float* W) {
#pragma unroll
    for (int tt = 0; tt < 2; ++tt) {
      const float* wr = W + ((wv * 2 + tt) * 16 + l15) * 256 + lg * 8;
#pragma unroll
      for (int s = 0; s < 8; ++s) {
        *(float4*)&wreg[tt][s * 8] = *(const float4*)(wr + s * 32);
        *(float4*)&wreg[tt][s * 8 + 4] = *(const float4*)(wr + s * 32 + 4);
      }
    }
  };

  // issue layer-0 weight loads first; c-staging below hides their latency
  prefetch(Ws[0]);

  // stage c: ws cT[o][b] fp32 -> xh/xl[b][o]
  const float* cws = ws + CT_OFF;
  for (int idx = tid; idx < NH * NB; idx += 512) {
    int o = idx >> 6, b = idx & 63;
    float f = cws[idx];
    short h = bfh(f);
    xh[b * XS + o] = (unsigned short)h;
    xl[b * XS + o] = (unsigned short)bfh(f - bff(h));
  }
  if (tid < NB) tcl[tid] = 0.f;
  __syncthreads();

#pragma unroll
  for (int L = 0; L < 4; ++L) {
    // pin: nothing below may hoist above, nothing above (the prefetched
    // loads) may sink below -> all 32 loads are in flight together.
    __builtin_amdgcn_sched_barrier(0);

    f32x4 acc[2][4];
#pragma unroll
    for (int tt = 0; tt < 2; ++tt)
#pragma unroll
      for (int n = 0; n < 4; ++n) acc[tt][n] = (f32x4){0.f, 0.f, 0.f, 0.f};

#pragma unroll
    for (int s = 0; s < 8; ++s) {
      short8b bh[4], bl[4];
#pragma unroll
      for (int n = 0; n < 4; ++n) {
        const int lidx = (n * 16 + l15) * XS + s * 32 + lg * 8;
        bh[n] = *(const short8b*)(xh + lidx);  // ds_read_b128
        bl[n] = *(const short8b*)(xl + lidx);
      }
#pragma unroll
      for (int tt = 0; tt < 2; ++tt) {
        short8b ah, al;
#pragma unroll
        for (int i = 0; i < 8; ++i) {
          float f = wreg[tt][s * 8 + i];
          short h = bfh(f);
          ah[i] = h;
          al[i] = bfh(f - bff(h));
        }
#pragma unroll
        for (int n = 0; n < 4; ++n) {
          acc[tt][n] = __builtin_amdgcn_mfma_f32_16x16x32_bf16(
              ah, bh[n], acc[tt][n], 0, 0, 0);
          acc[tt][n] = __builtin_amdgcn_mfma_f32_16x16x32_bf16(
              ah, bl[n], acc[tt][n], 0, 0, 0);
          acc[tt][n] = __builtin_amdgcn_mfma_f32_16x16x32_bf16(
              al, bh[n], acc[tt][n], 0, 0, 0);
        }
      }
    }

    // wreg is dead now: issue next layer's loads; BN below hides latency
    if (L < 3) prefetch(Ws[L + 1]);

    __syncthreads();  // all LDS reads of x done before overwrite

    if (L < 3) {
#pragma unroll
      for (int tt = 0; tt < 2; ++tt) {
#pragma unroll
        for (int r = 0; r < 4; ++r) {
          const int o = (wv * 2 + tt) * 16 + lg * 4 + r;
          float a0 = acc[tt][0][r], a1 = acc[tt][1][r];
          float a2 = acc[tt][2][r], a3 = acc[tt][3][r];
          float s1 = a0 + a1 + a2 + a3;
          s1 += __shfl_xor(s1, 1);
          s1 += __shfl_xor(s1, 2);
          s1 += __shfl_xor(s1, 4);
          s1 += __shfl_xor(s1, 8);
          float m = s1 * (1.f / 64.f);
          float d0 = a0 - m, d1 = a1 - m, d2 = a2 - m, d3 = a3 - m;
          float s2 = d0 * d0 + d1 * d1 + d2 * d2 + d3 * d3;
          s2 += __shfl_xor(s2, 1);
          s2 += __shfl_xor(s2, 2);
          s2 += __shfl_xor(s2, 4);
          s2 += __shfl_xor(s2, 8);
          float sc = Gs[L][o] * rsqrtf(s2 * (1.f / 64.f) + EPS_BN);
          float bo = Bs[L][o];
          float hv[4] = {fmaxf(d0 * sc + bo, 0.f), fmaxf(d1 * sc + bo, 0.f),
                         fmaxf(d2 * sc + bo, 0.f), fmaxf(d3 * sc + bo, 0.f)};
#pragma unroll
          for (int n = 0; n < 4; ++n) {
            short h = bfh(hv[n]);
            xh[(n * 16 + l15) * XS + o] = (unsigned short)h;
            xl[(n * 16 + l15) * XS + o] =
                (unsigned short)bfh(hv[n] - bff(h));
          }
        }
      }
      __syncthreads();
    } else {
      // layer 3: BN+relu, then tc[b] = b4 + sum_o w4[o]*h[o][b]
      float part[4] = {0.f, 0.f, 0.f, 0.f};
#pragma unroll
      for (int tt = 0; tt < 2; ++tt) {
#pragma unroll
        for (int r = 0; r < 4; ++r) {
          const int o = (wv * 2 + tt) * 16 + lg * 4 + r;
          float a0 = acc[tt][0][r], a1 = acc[tt][1][r];
          float a2 = acc[tt][2][r], a3 = acc[tt][3][r];
          float s1 = a0 + a1 + a2 + a3;
          s1 += __shfl_xor(s1, 1);
          s1 += __shfl_xor(s1, 2);
          s1 += __shfl_xor(s1, 4);
          s1 += __shfl_xor(s1, 8);
          float m = s1 * (1.f / 64.f);
          float d0 = a0 - m, d1 = a1 - m, d2 = a2 - m, d3 = a3 - m;
          float s2 = d0 * d0 + d1 * d1 + d2 * d2 + d3 * d3;
          s2 += __shfl_xor(s2, 1);
          s2 += __shfl_xor(s2, 2);
          s2 += __shfl_xor(s2, 4);
          s2 += __shfl_xor(s2, 8);
          float sc = Gs[3][o] * rsqrtf(s2 * (1.f / 64.f) + EPS_BN);
          float bo = Bs[3][o];
          float w4o = w4[o];
          part[0] += fmaxf(d0 * sc + bo, 0.f) * w4o;
          part[1] += fmaxf(d1 * sc + bo, 0.f) * w4o;
          part[2] += fmaxf(d2 * sc + bo, 0.f) * w4o;
          part[3] += fmaxf(d3 * sc + bo, 0.f) * w4o;
        }
      }
#pragma unroll
      for (int n = 0; n < 4; ++n) {
        part[n] += __shfl_xor(part[n], 16);
        part[n] += __shfl_xor(part[n], 32);
      }
      if (lg == 0) {
#pragma unroll
        for (int n = 0; n < 4; ++n) atomicAdd(&tcl[n * 16 + l15], part[n]);
      }
      __syncthreads();
      if (tid < NB) out[tid] = b4[0] + tcl[tid];
    }
  }
}

extern "C" void kernel_launch(void* const* d_in, const int* in_sizes, int n_in,
                              void* d_out, int out_size, void* d_ws,
                              size_t ws_size, hipStream_t stream) {
  const float* xyz = (const float*)d_in[0];
  const float* pts = (const float*)d_in[1];
  const float* l3 = (const float*)d_in[2];
  const float* temp = (const float*)d_in[3];
  const float* w0 = (const float*)d_in[4];
  const float* g0 = (const float*)d_in[6];
  const float* be0 = (const float*)d_in[7];
  const float* w1 = (const float*)d_in[8];
  const float* g1 = (const float*)d_in[10];
  const float* be1 = (const float*)d_in[11];
  const float* w2 = (const float*)d_in[12];
  const float* g2 = (const float*)d_in[14];
  const float* be2 = (const float*)d_in[15];
  const float* w3 = (const float*)d_in[16];
  const float* g3 = (const float*)d_in[18];
  const float* be3 = (const float*)d_in[19];
  const float* w4 = (const float*)d_in[20];
  const float* b4 = (const float*)d_in[21];

  float* out = (float*)d_out;
  float* ws = (float*)d_ws;

  k1_scan_misc_copy<<<K1_GRID, 256, 0, stream>>>(xyz, temp, l3, pts, out, ws);
  k2_corr<<<512, 256, 0, stream>>>(pts, out, ws);
  k3_mlp<<<1, 512, 0, stream>>>(ws, w0, g0, be0, w1, g1, be1, w2, g2, be2, w3,
                                g3, be3, w4, b4, out);
}

// Round 8
// 172.193 us; speedup vs baseline: 1.1105x; 1.1105x over previous
//
#include <hip/hip_runtime.h>

// Problem constants
#define NB 64
#define NP 500
#define NC 128
#define NH 256
#define EPS_BN 1e-5f

// Edge-list geometry: 64 batches x 8 j-tiles, cap 1024 edges/segment
#define SEGS 8
#define CAPE 1024

// ws layout (float/int words)
#define EDGE_OFF 0
#define CNT_OFF (NB * SEGS * CAPE)   // 524288 (512 words)
#define CT_OFF (CNT_OFF + 512)       // c matrix, feature-major [256][64]
#define H1_OFF (CT_OFF + NH * NB)
#define H2_OFF (H1_OFF + NH * NB)

// Output layout: tc[64] | tsys[64] | l2_points[4096000] | correlation[8192]
#define OUT_PTS_OFF 128
#define OUT_CORR_OFF 4096128
#define TOTAL_F4 1024000  // 4,096,000 floats / 4

// k1 grid: scan 0..511 | misc 512..575 | copy 576..1599
#define SCAN_BLKS 512
#define MISC_END 576
#define K1_COPY 1024
#define K1_GRID (MISC_END + K1_COPY)

typedef __attribute__((ext_vector_type(8))) short short8b;  // 8 bf16
typedef __attribute__((ext_vector_type(4))) float f32x4;

__device__ __forceinline__ short bfh(float f) {
  return (short)(__builtin_bit_cast(unsigned, f) >> 16);  // truncate to bf16
}
__device__ __forceinline__ float bff(short h) {
  return __builtin_bit_cast(float, ((unsigned)(unsigned short)h) << 16);
}

// ---------------------------------------------------------------------------
// K1: pair scan (512 = b x 8 j-tiles) + per-batch misc (64) + full pts copy.
// (Verbatim harness-verified; misc regains the round-0-verified tc init.)
// ---------------------------------------------------------------------------
__global__ __launch_bounds__(256) void k1_scan_misc_copy(
    const float* __restrict__ xyz,    // [B,3,N]
    const float* __restrict__ temp,   // [B,1,N]
    const float* __restrict__ l3,     // [B,C]
    const float* __restrict__ b4,     // [1] fc_lt4_b
    const float* __restrict__ pts,    // [B,C,N] l2_points
    float* __restrict__ out,
    float* __restrict__ ws) {
  const int blk = blockIdx.x;
  const int tid = threadIdx.x;

  if (blk < SCAN_BLKS) {
    const int b = blk >> 3;
    const int jt = blk & 7;
    __shared__ float4 pt[NP];  // x,y,z,s
    __shared__ int lcnt;
    if (tid == 0) lcnt = 0;
    const float* xr = xyz + b * 1500;
    for (int idx = tid; idx < NP; idx += 256) {
      float x = xr[idx], y = xr[500 + idx], z = xr[1000 + idx];
      pt[idx] = make_float4(x, y, z, x * x + y * y + z * z);
    }
    __syncthreads();

    const int j0 = jt * 63;
    const int j1 = (j0 + 63 < NP) ? j0 + 63 : NP;
    const int i0 = tid;
    const int i1 = tid + 256;
    float4 p0 = pt[i0];
    float4 p1 = (i1 < NP) ? pt[i1] : make_float4(0.f, 0.f, 0.f, 0.f);
    int* eseg = (int*)ws + EDGE_OFF + (b * SEGS + jt) * CAPE;

    for (int j = j0; j < j1; ++j) {
      float4 q = pt[j];  // wave-uniform -> LDS broadcast
      if (i0 < j) {
        float sq = p0.w + q.w - 2.f * (p0.x * q.x + p0.y * q.y + p0.z * q.z);
        float d = sqrtf(fabsf(sq));
        if (d > 0.19f && d < 0.21f) {
          int e = atomicAdd(&lcnt, 1);
          if (e < CAPE) eseg[e] = (i0 << 16) | j;
        }
      }
      if (i1 < j) {  // implies i1 < 500
        float sq = p1.w + q.w - 2.f * (p1.x * q.x + p1.y * q.y + p1.z * q.z);
        float d = sqrtf(fabsf(sq));
        if (d > 0.19f && d < 0.21f) {
          int e = atomicAdd(&lcnt, 1);
          if (e < CAPE) eseg[e] = (i1 << 16) | j;
        }
      }
    }
    __syncthreads();
    if (tid == 0) {
      int c = lcnt < CAPE ? lcnt : CAPE;
      ((int*)ws)[CNT_OFF + b * SEGS + jt] = c;
    }
  } else if (blk < MISC_END) {
    // misc per batch: tsys, cT sa4 rows, tc bias init
    const int b = blk - SCAN_BLKS;
    float sum = 0.f;
    for (int i = tid; i < NP; i += 256) sum += temp[b * NP + i];
    for (int off = 32; off; off >>= 1) sum += __shfl_xor(sum, off);
    __shared__ float wsum[4];
    if ((tid & 63) == 0) wsum[tid >> 6] = sum;
    __syncthreads();
    if (tid == 0)
      out[64 + b] = (wsum[0] + wsum[1] + wsum[2] + wsum[3]) * (1.f / 500.f);
    if (tid < NC) ws[CT_OFF + (NC + tid) * 64 + b] = l3[b * NC + tid];
    if (tid == 0) out[b] = b4[0];  // tc starts at bias; layer-3 atomicAdds
  } else {
    // copy all of l2_points -> out (also warms LLC for k2's re-read)
    const int cb = blk - MISC_END;
    const float4* src = (const float4*)pts;
    float4* dst = (float4*)(out + OUT_PTS_OFF);
    for (int idx = cb * 256 + tid; idx < TOTAL_F4; idx += K1_COPY * 256)
      dst[idx] = src[idx];
  }
}

// ---------------------------------------------------------------------------
// K2: correlation (512 = b x 8 chan-groups). Verbatim verified edge math.
// ---------------------------------------------------------------------------
__global__ __launch_bounds__(256) void k2_corr(
    const float* __restrict__ data,  // l2_points [B,C,N]
    float* __restrict__ out,
    float* __restrict__ ws) {
  const int blk = blockIdx.x;
  const int tid = threadIdx.x;
  const int b = blk >> 3;
  const int c0 = (blk & 7) * 16;
  __shared__ float dT[NP * 20];  // [j][c] for 16 channels, stride 20
  __shared__ float corrp[16];
  if (tid < 16) corrp[tid] = 0.f;

  const float4* in4 = (const float4*)(data + (size_t)b * 64000 + c0 * 500);
  for (int idx = tid; idx < 2000; idx += 256) {
    float4 v = in4[idx];
    int c = idx / 125;
    int j = (idx - c * 125) * 4;
    dT[(j + 0) * 20 + c] = v.x;
    dT[(j + 1) * 20 + c] = v.y;
    dT[(j + 2) * 20 + c] = v.z;
    dT[(j + 3) * 20 + c] = v.w;
  }
  __syncthreads();

  const int quad = tid & 3;
  const int slot = tid >> 2;
  float4 acc = make_float4(0.f, 0.f, 0.f, 0.f);
  const int* cnts = (const int*)ws + CNT_OFF + b * SEGS;
  int Etot = 0;
  for (int seg = 0; seg < SEGS; ++seg) {
    int E = cnts[seg];
    Etot += E;
    const int* eseg = (const int*)ws + EDGE_OFF + (b * SEGS + seg) * CAPE;
    for (int e = slot; e < E; e += 64) {
      int ij = eseg[e];
      int i = ij >> 16, j = ij & 0xffff;
      const float4 a = *(const float4*)(dT + i * 20 + quad * 4);
      const float4 c4 = *(const float4*)(dT + j * 20 + quad * 4);
      acc.x += a.x * c4.x;
      acc.y += a.y * c4.y;
      acc.z += a.z * c4.z;
      acc.w += a.w * c4.w;
    }
  }
  for (int off = 4; off < 64; off <<= 1) {
    acc.x += __shfl_xor(acc.x, off);
    acc.y += __shfl_xor(acc.y, off);
    acc.z += __shfl_xor(acc.z, off);
    acc.w += __shfl_xor(acc.w, off);
  }
  if ((tid & 63) < 4) {
    atomicAdd(&corrp[quad * 4 + 0], acc.x);
    atomicAdd(&corrp[quad * 4 + 1], acc.y);
    atomicAdd(&corrp[quad * 4 + 2], acc.z);
    atomicAdd(&corrp[quad * 4 + 3], acc.w);
  }
  __syncthreads();
  if (tid < 16) {
    float denom = fmaxf(2.f * (float)Etot, 1.f);  // ordered count = 2E
    float v = 2.f * corrp[tid] / denom;           // ordered sum = 2*upper
    out[OUT_CORR_OFF + b * NC + c0 + tid] = v;
    ws[CT_OFF + (c0 + tid) * 64 + b] = v;
  }
}

// ---------------------------------------------------------------------------
// lmfma: one MLP layer via MFMA. Grid = 16 blocks x 64 threads (1 wave).
// Block ot owns output features [16*ot, 16*ot+16) -> BN is block-local.
// Weight slice per block = 16 KB = 16 dwordx4/lane, fetched concurrently by
// 16 blocks across CUs (structural MLP latency-hiding: no compiler
// scheduling dependence, unlike the single-workgroup k3 of rounds 4-7).
// Math/fragment maps verbatim from the harness-verified k3 (bf16x3 split,
// A row = ot*16+l15, k = s*32+lg*8+i; D: o = ot*16+lg*4+r, b = n*16+l15;
// bias omitted — BN mean-subtract cancels it; BN reduce = shfl_xor{1,2,4,8}).
// Activations fp32 feature-major [256][64] in ws (verified format).
// If w4 != null: layer 3 -> atomicAdd(tc[b], w4[o]*h) (tc preinit to b4).
// ---------------------------------------------------------------------------
__global__ __launch_bounds__(64) void lmfma(
    const float* __restrict__ xT, const float* __restrict__ W,
    const float* __restrict__ g, const float* __restrict__ be,
    float* __restrict__ yT, const float* __restrict__ w4,
    float* __restrict__ tc) {
  const int lane = threadIdx.x;
  const int l15 = lane & 15;
  const int lg = lane >> 4;
  const int ot = blockIdx.x;  // 0..15

  // ---- A-fragments: 16 dwordx4 (independent, one latency), then convert
  short8b ah[8], al[8];
  const float* wr = W + (ot * 16 + l15) * 256 + lg * 8;
#pragma unroll
  for (int s = 0; s < 8; ++s) {
    float4 wa = *(const float4*)(wr + s * 32);
    float4 wb = *(const float4*)(wr + s * 32 + 4);
#pragma unroll
    for (int i = 0; i < 4; ++i) {
      float fa = ((const float*)&wa)[i];
      short h = bfh(fa);
      ah[s][i] = h;
      al[s][i] = bfh(fa - bff(h));
      float fb = ((const float*)&wb)[i];
      h = bfh(fb);
      ah[s][4 + i] = h;
      al[s][4 + i] = bfh(fb - bff(h));
    }
  }

  f32x4 acc[4];
#pragma unroll
  for (int n = 0; n < 4; ++n) acc[n] = (f32x4){0.f, 0.f, 0.f, 0.f};

#pragma unroll
  for (int s = 0; s < 8; ++s) {
    short8b bh[4], bl[4];
#pragma unroll
    for (int n = 0; n < 4; ++n) {
#pragma unroll
      for (int i = 0; i < 8; ++i) {
        float f = xT[(s * 32 + lg * 8 + i) * 64 + n * 16 + l15];
        short h = bfh(f);
        bh[n][i] = h;
        bl[n][i] = bfh(f - bff(h));
      }
    }
#pragma unroll
    for (int n = 0; n < 4; ++n) {
      acc[n] = __builtin_amdgcn_mfma_f32_16x16x32_bf16(ah[s], bh[n], acc[n],
                                                       0, 0, 0);
      acc[n] = __builtin_amdgcn_mfma_f32_16x16x32_bf16(ah[s], bl[n], acc[n],
                                                       0, 0, 0);
      acc[n] = __builtin_amdgcn_mfma_f32_16x16x32_bf16(al[s], bh[n], acc[n],
                                                       0, 0, 0);
    }
  }

  if (!w4) {
#pragma unroll
    for (int r = 0; r < 4; ++r) {
      const int o = ot * 16 + lg * 4 + r;
      float a0 = acc[0][r], a1 = acc[1][r], a2 = acc[2][r], a3 = acc[3][r];
      float s1 = a0 + a1 + a2 + a3;
      s1 += __shfl_xor(s1, 1);
      s1 += __shfl_xor(s1, 2);
      s1 += __shfl_xor(s1, 4);
      s1 += __shfl_xor(s1, 8);
      float m = s1 * (1.f / 64.f);
      float d0 = a0 - m, d1 = a1 - m, d2 = a2 - m, d3 = a3 - m;
      float s2 = d0 * d0 + d1 * d1 + d2 * d2 + d3 * d3;
      s2 += __shfl_xor(s2, 1);
      s2 += __shfl_xor(s2, 2);
      s2 += __shfl_xor(s2, 4);
      s2 += __shfl_xor(s2, 8);
      float sc = g[o] * rsqrtf(s2 * (1.f / 64.f) + EPS_BN);
      float bo = be[o];
      yT[o * 64 + 0 * 16 + l15] = fmaxf(d0 * sc + bo, 0.f);
      yT[o * 64 + 1 * 16 + l15] = fmaxf(d1 * sc + bo, 0.f);
      yT[o * 64 + 2 * 16 + l15] = fmaxf(d2 * sc + bo, 0.f);
      yT[o * 64 + 3 * 16 + l15] = fmaxf(d3 * sc + bo, 0.f);
    }
  } else {
    float part[4] = {0.f, 0.f, 0.f, 0.f};
#pragma unroll
    for (int r = 0; r < 4; ++r) {
      const int o = ot * 16 + lg * 4 + r;
      float a0 = acc[0][r], a1 = acc[1][r], a2 = acc[2][r], a3 = acc[3][r];
      float s1 = a0 + a1 + a2 + a3;
      s1 += __shfl_xor(s1, 1);
      s1 += __shfl_xor(s1, 2);
      s1 += __shfl_xor(s1, 4);
      s1 += __shfl_xor(s1, 8);
      float m = s1 * (1.f / 64.f);
      float d0 = a0 - m, d1 = a1 - m, d2 = a2 - m, d3 = a3 - m;
      float s2 = d0 * d0 + d1 * d1 + d2 * d2 + d3 * d3;
      s2 += __shfl_xor(s2, 1);
      s2 += __shfl_xor(s2, 2);
      s2 += __shfl_xor(s2, 4);
      s2 += __shfl_xor(s2, 8);
      float sc = g[o] * rsqrtf(s2 * (1.f / 64.f) + EPS_BN);
      float bo = be[o];
      float w4o = w4[o];
      part[0] += fmaxf(d0 * sc + bo, 0.f) * w4o;
      part[1] += fmaxf(d1 * sc + bo, 0.f) * w4o;
      part[2] += fmaxf(d2 * sc + bo, 0.f) * w4o;
      part[3] += fmaxf(d3 * sc + bo, 0.f) * w4o;
    }
#pragma unroll
    for (int n = 0; n < 4; ++n) {
      part[n] += __shfl_xor(part[n], 16);
      part[n] += __shfl_xor(part[n], 32);
    }
    if (lg == 0) {
#pragma unroll
      for (int n = 0; n < 4; ++n) atomicAdd(&tc[n * 16 + l15], part[n]);
    }
  }
}

extern "C" void kernel_launch(void* const* d_in, const int* in_sizes, int n_in,
                              void* d_out, int out_size, void* d_ws,
                              size_t ws_size, hipStream_t stream) {
  const float* xyz = (const float*)d_in[0];
  const float* pts = (const float*)d_in[1];
  const float* l3 = (const float*)d_in[2];
  const float* temp = (const float*)d_in[3];
  const float* w0 = (const float*)d_in[4];
  const float* g0 = (const float*)d_in[6];
  const float* be0 = (const float*)d_in[7];
  const float* w1 = (const float*)d_in[8];
  const float* g1 = (const float*)d_in[10];
  const float* be1 = (const float*)d_in[11];
  const float* w2 = (const float*)d_in[12];
  const float* g2 = (const float*)d_in[14];
  const float* be2 = (const float*)d_in[15];
  const float* w3 = (const float*)d_in[16];
  const float* g3 = (const float*)d_in[18];
  const float* be3 = (const float*)d_in[19];
  const float* w4 = (const float*)d_in[20];
  const float* b4 = (const float*)d_in[21];

  float* out = (float*)d_out;
  float* ws = (float*)d_ws;
  float* cT = ws + CT_OFF;
  float* hA = ws + H1_OFF;
  float* hB = ws + H2_OFF;

  k1_scan_misc_copy<<<K1_GRID, 256, 0, stream>>>(xyz, temp, l3, b4, pts, out,
                                                 ws);
  k2_corr<<<512, 256, 0, stream>>>(pts, out, ws);
  lmfma<<<16, 64, 0, stream>>>(cT, w0, g0, be0, hA, nullptr, nullptr);
  lmfma<<<16, 64, 0, stream>>>(hA, w1, g1, be1, hB, nullptr, nullptr);
  lmfma<<<16, 64, 0, stream>>>(hB, w2, g2, be2, hA, nullptr, nullptr);
  lmfma<<<16, 64, 0, stream>>>(hA, w3, g3, be3, nullptr, w4, out);
}